// Round 4
// baseline (200.738 us; speedup 1.0000x reference)
//
#include <hip/hip_runtime.h>

// mixture/target/noise: (N, 2, C, T, F) float32
#define Nn 4
#define Cc 8
#define Tt 256
#define Ff 513
#define TFs (Tt * Ff)      // 131328
#define NPAIR 36           // upper triangle of 8x8 Hermitian

// ---------------------------------------------------------------------------
// Stage 1: partial covariances. One block = 2 waves (same CU -> shared L1).
// Wave W handles Hermitian rows {2W, 7-2W, 2W+1, 6-2W} = 18 pairs, 36 VGPR acc.
// Partial layout: [inp][n][chunk][p][ri][f]  (f contiguous -> coalesced)
// ---------------------------------------------------------------------------
template <int W>
__device__ __forceinline__ void cov2_body(const float* __restrict__ base,
                                          float* __restrict__ dst,
                                          int t0, int tchunk)
{
    constexpr int G0 = 2 * W;
    constexpr int G1 = 2 * W + 1;
    constexpr int H0 = 7 - G0;
    constexpr int H1 = 7 - G1;
    float ar[18], ai[18];
#pragma unroll
    for (int s = 0; s < 18; ++s) { ar[s] = 0.f; ai[s] = 0.f; }

    const float* bt = base + (size_t)t0 * Ff;
    for (int tt = 0; tt < tchunk; ++tt) {
        float re[8], im[8];
#pragma unroll
        for (int c = G0; c < 8; ++c) {
            re[c] = bt[(size_t)c * TFs];
            im[c] = bt[(size_t)(Cc + c) * TFs];
        }
        int s = 0;
#pragma unroll
        for (int d = G0; d < 8; ++d, ++s) {   // row G0
            ar[s] += re[G0] * re[d] + im[G0] * im[d];
            ai[s] += im[G0] * re[d] - re[G0] * im[d];
        }
#pragma unroll
        for (int d = H0; d < 8; ++d, ++s) {   // row 7-G0
            ar[s] += re[H0] * re[d] + im[H0] * im[d];
            ai[s] += im[H0] * re[d] - re[H0] * im[d];
        }
#pragma unroll
        for (int d = G1; d < 8; ++d, ++s) {   // row G1
            ar[s] += re[G1] * re[d] + im[G1] * im[d];
            ai[s] += im[G1] * re[d] - re[G1] * im[d];
        }
#pragma unroll
        for (int d = H1; d < 8; ++d, ++s) {   // row 7-G1
            ar[s] += re[H1] * re[d] + im[H1] * im[d];
            ai[s] += im[H1] * re[d] - re[H1] * im[d];
        }
        bt += Ff;
    }

    int s = 0;
#pragma unroll
    for (int d = G0; d < 8; ++d, ++s) {
        const int p = G0 * 8 - G0 * (G0 - 1) / 2 + (d - G0);
        dst[(size_t)(p * 2 + 0) * Ff] = ar[s];
        dst[(size_t)(p * 2 + 1) * Ff] = ai[s];
    }
#pragma unroll
    for (int d = H0; d < 8; ++d, ++s) {
        const int p = H0 * 8 - H0 * (H0 - 1) / 2 + (d - H0);
        dst[(size_t)(p * 2 + 0) * Ff] = ar[s];
        dst[(size_t)(p * 2 + 1) * Ff] = ai[s];
    }
#pragma unroll
    for (int d = G1; d < 8; ++d, ++s) {
        const int p = G1 * 8 - G1 * (G1 - 1) / 2 + (d - G1);
        dst[(size_t)(p * 2 + 0) * Ff] = ar[s];
        dst[(size_t)(p * 2 + 1) * Ff] = ai[s];
    }
#pragma unroll
    for (int d = H1; d < 8; ++d, ++s) {
        const int p = H1 * 8 - H1 * (H1 - 1) / 2 + (d - H1);
        dst[(size_t)(p * 2 + 0) * Ff] = ar[s];
        dst[(size_t)(p * 2 + 1) * Ff] = ai[s];
    }
}

__global__ __launch_bounds__(128) void cov_partial(
    const float* __restrict__ target, const float* __restrict__ noise,
    float* __restrict__ partial, int nchunk, int tchunk)
{
    int f = blockIdx.x * 64 + (threadIdx.x & 63);
    if (f >= Ff) return;
    int w = threadIdx.x >> 6;
    int n = blockIdx.y;
    int z = blockIdx.z;
    int inp = z & 1;
    int chunk = z >> 1;

    const float* src = inp ? noise : target;
    const float* base = src + (size_t)n * 2 * Cc * TFs + f;
    float* dst = partial +
        ((((size_t)inp * Nn + n) * nchunk + chunk) * (NPAIR * 2)) * Ff + f;
    int t0 = chunk * tchunk;

    if (w == 0) cov2_body<0>(base, dst, t0, tchunk);
    else        cov2_body<1>(base, dst, t0, tchunk);
}

// ---------------------------------------------------------------------------
// Stage 2: fused chunk-reduce + register-resident Gauss-Jordan.
// Block = 256 threads = 4 waves = 16 problems (f's). Reduce phase: 16
// consecutive lanes read 16 consecutive f's -> 64B-coalesced. GJ: 16 lanes =
// 16 columns of augmented [phiN | phiT]; shuffle broadcasts, no barriers.
// ---------------------------------------------------------------------------
__global__ __launch_bounds__(256) void mvdr_weights(
    const float* __restrict__ partial, const int* __restrict__ ref_ptr,
    float2* __restrict__ wconj, int nchunk)
{
    const int tid = threadIdx.x;
    const int n = blockIdx.y;
    const int fbase = blockIdx.x * 16;

    __shared__ float cov[16][144];   // [prob][ target 72 | noise 72 ]

    {
        int f_off = tid & 15;
        int vrow = tid >> 4;          // 0..15
        int f = fbase + f_off;
#pragma unroll
        for (int b = 0; b < 9; ++b) {
            int v = b * 16 + vrow;    // 0..143
            int inp = v >= 72 ? 1 : 0;
            int p = inp ? v - 72 : v;
            float acc = 0.f;
            if (f < Ff) {
                const float* src = partial +
                    (((size_t)inp * Nn + n) * nchunk * 72 + p) * Ff + f;
                for (int ch = 0; ch < nchunk; ++ch)
                    acc += src[(size_t)ch * 72 * Ff];
            }
            cov[f_off][v] = acc;
        }
    }
    __syncthreads();

    const int prob = tid >> 4;        // 0..15
    const int col = tid & 15;
    const int f = fbase + prob;

    const float invT = 1.0f / (float)Tt;
    const float dl = 0.001f / 1.41421356237309515f;  // 0.001/sqrt(2)

    float Ar[8], Ai[8];
    {
        const bool left = (col < 8);            // left = phiN, right = phiT
        const int c = left ? col : col - 8;
        const float* cv = &cov[prob][left ? 72 : 0];
#pragma unroll
        for (int r = 0; r < 8; ++r) {
            int lo = r <= c ? r : c, hi = r <= c ? c : r;
            int p = lo * 8 - lo * (lo - 1) / 2 + (hi - lo);
            float vr = cv[2 * p] * invT;
            float vi = cv[2 * p + 1] * invT;
            if (r > c) vi = -vi;                // Hermitian reconstruction
            if (left && r == c) { vr += dl; vi += dl; }  // complex diag load
            Ar[r] = vr; Ai[r] = vi;
        }
    }

#pragma unroll
    for (int k = 0; k < 8; ++k) {
        int best = k;
        float bm = Ar[k] * Ar[k] + Ai[k] * Ai[k];
#pragma unroll
        for (int j = 0; j < 8; ++j) {
            if (j > k) {
                float m = Ar[j] * Ar[j] + Ai[j] * Ai[j];
                if (m > bm) { bm = m; best = j; }
            }
        }
        int bk = __shfl(best, k, 16);

        float tr = Ar[k], ti = Ai[k];
#pragma unroll
        for (int j = 0; j < 8; ++j) {
            if (j == bk && j != k) {
                Ar[k] = Ar[j]; Ai[k] = Ai[j];
                Ar[j] = tr;    Ai[j] = ti;
            }
        }

        float pr = __shfl(Ar[k], k, 16);
        float pi = __shfl(Ai[k], k, 16);
        float d = pr * pr + pi * pi;
        float ir = pr / d, ii = -pi / d;
        float nr = Ar[k] * ir - Ai[k] * ii;
        float ni = Ar[k] * ii + Ai[k] * ir;
        Ar[k] = nr; Ai[k] = ni;

#pragma unroll
        for (int r = 0; r < 8; ++r) {
            float fr = __shfl(Ar[r], k, 16);
            float fi = __shfl(Ai[r], k, 16);
            if (r != k) {
                Ar[r] -= fr * Ar[k] - fi * Ai[k];
                Ai[r] -= fr * Ai[k] + fi * Ar[k];
            }
        }
    }

    // trace(G): lane 8+j holds G[j][j]; butterfly over the 16-lane group
    float tlr = 0.f, tli = 0.f;
    if (col >= 8) { tlr = Ar[col - 8]; tli = Ai[col - 8]; }
#pragma unroll
    for (int off = 1; off < 16; off <<= 1) {
        tlr += __shfl_xor(tlr, off, 16);
        tli += __shfl_xor(tli, off, 16);
    }

    int ref = *ref_ptr;
    if (col == 8 + ref && f < Ff) {
        float den = tlr * tlr + tli * tli;
        float2* wp = wconj + ((size_t)n * Ff + f) * 8;
#pragma unroll
        for (int r = 0; r < 8; ++r) {
            float wx = (Ar[r] * tlr + Ai[r] * tli) / den;
            float wy = (Ai[r] * tlr - Ar[r] * tli) / den;
            wp[r] = make_float2(wx, -wy);   // conj(W)
        }
    }
}

// ---------------------------------------------------------------------------
// Stage 3: X_bf(n,t,f) = sum_c conj(W)(n,f,c) * y(n,c,t,f), float2 over flat
// (t,f). Adjacent flat positions are memory-adjacent in y and out.
// ---------------------------------------------------------------------------
__global__ __launch_bounds__(256) void beamform(
    const float* __restrict__ y, const float2* __restrict__ wconj,
    float* __restrict__ out)
{
    int idx = blockIdx.x * 256 + threadIdx.x;   // < N*TFs/2 = 262656
    int n = idx / (TFs / 2);
    int m = (idx - n * (TFs / 2)) * 2;          // even flat position t*Ff+f
    int f0 = m % Ff;
    int f1 = (f0 + 1 == Ff) ? 0 : f0 + 1;

    const float2* yb = (const float2*)y + ((size_t)n * 2 * Cc * TFs + m) / 2;
    const float2* w0 = wconj + ((size_t)n * Ff + f0) * 8;
    const float2* w1 = wconj + ((size_t)n * Ff + f1) * 8;

    float xr0 = 0.f, xi0 = 0.f, xr1 = 0.f, xi1 = 0.f;
#pragma unroll
    for (int c = 0; c < Cc; ++c) {
        float2 yre = yb[(size_t)c * (TFs / 2)];
        float2 yim = yb[(size_t)(Cc + c) * (TFs / 2)];
        float2 a = w0[c], b = w1[c];
        xr0 += a.x * yre.x - a.y * yim.x;
        xi0 += a.x * yim.x + a.y * yre.x;
        xr1 += b.x * yre.y - b.y * yim.y;
        xi1 += b.x * yim.y + b.y * yre.y;
    }
    size_t ob = ((size_t)n * 2 * TFs + m) / 2;   // float2 units
    ((float2*)out)[ob] = make_float2(xr0, xr1);           // real plane
    ((float2*)out)[ob + TFs / 2] = make_float2(xi0, xi1); // imag plane
}

extern "C" void kernel_launch(void* const* d_in, const int* in_sizes, int n_in,
                              void* d_out, int out_size, void* d_ws, size_t ws_size,
                              hipStream_t stream) {
    const float* mixture = (const float*)d_in[0];
    const float* target  = (const float*)d_in[1];
    const float* noise   = (const float*)d_in[2];
    const int*   refp    = (const int*)d_in[3];
    float* out = (float*)d_out;

    const size_t wconj_bytes = (size_t)Nn * Ff * 8 * sizeof(float2);
    int nchunk = 8;
    while (nchunk > 1 &&
           (size_t)2 * Nn * nchunk * 72 * Ff * sizeof(float) + wconj_bytes > ws_size)
        nchunk >>= 1;
    int tchunk = Tt / nchunk;

    float*  partial = (float*)d_ws;
    float2* wconj = (float2*)((char*)d_ws +
                              (size_t)2 * Nn * nchunk * 72 * Ff * sizeof(float));

    cov_partial<<<dim3(9, Nn, nchunk * 2), 128, 0, stream>>>(
        target, noise, partial, nchunk, tchunk);
    mvdr_weights<<<dim3((Ff + 15) / 16, Nn), 256, 0, stream>>>(
        partial, refp, wconj, nchunk);
    beamform<<<dim3((Nn * TFs / 2) / 256), 256, 0, stream>>>(mixture, wconj, out);
}

// Round 5
// 175.284 us; speedup vs baseline: 1.1452x; 1.1452x over previous
//
#include <hip/hip_runtime.h>

// mixture/target/noise: (N, 2, C, T, F) float32
#define Nn 4
#define Cc 8
#define Tt 256
#define Ff 513
#define TFs (Tt * Ff)      // 131328
#define NPAIR 36           // upper triangle of 8x8 Hermitian
#define NCHUNK 32
#define TCHUNK (Tt / NCHUNK)   // 8

// cov buffer: [inp(2)][n(4)][p*2+ri (72)][f(513)] floats, atomically accumulated
#define COV_BYTES ((size_t)2 * Nn * 72 * Ff * 4)   // 1,181,952

// ---------------------------------------------------------------------------
// Stage 1: covariance accumulation. Pair-group G handles Hermitian rows
// {G, 7-G} = 9 pairs -> 18 acc VGPRs (no spill; 36-acc variant spilled in R4).
// 9216 one-wave blocks (~9 waves/SIMD) to hide load latency. Epilogue:
// atomicAdd into the final cov buffer (f-coalesced across the wave).
// ---------------------------------------------------------------------------
template <int G>
__device__ __forceinline__ void cov_body(const float* __restrict__ base,
                                         float* __restrict__ dst, int t0)
{
    constexpr int R2 = 7 - G;
    float ar[9], ai[9];
#pragma unroll
    for (int s = 0; s < 9; ++s) { ar[s] = 0.f; ai[s] = 0.f; }

    const float* bt = base + (size_t)t0 * Ff;
#pragma unroll
    for (int tt = 0; tt < TCHUNK; ++tt) {
        float re[8], im[8];
#pragma unroll
        for (int c = G; c < 8; ++c) {
            re[c] = bt[(size_t)c * TFs];
            im[c] = bt[(size_t)(Cc + c) * TFs];
        }
        int s = 0;
#pragma unroll
        for (int d = G; d < 8; ++d, ++s) {     // row G
            ar[s] += re[G] * re[d] + im[G] * im[d];
            ai[s] += im[G] * re[d] - re[G] * im[d];
        }
#pragma unroll
        for (int d = R2; d < 8; ++d, ++s) {    // row 7-G
            ar[s] += re[R2] * re[d] + im[R2] * im[d];
            ai[s] += im[R2] * re[d] - re[R2] * im[d];
        }
        bt += Ff;
    }

    int s = 0;
#pragma unroll
    for (int d = G; d < 8; ++d, ++s) {
        const int p = G * 8 - G * (G - 1) / 2 + (d - G);
        atomicAdd(dst + (size_t)(p * 2 + 0) * Ff, ar[s]);
        atomicAdd(dst + (size_t)(p * 2 + 1) * Ff, ai[s]);
    }
#pragma unroll
    for (int d = R2; d < 8; ++d, ++s) {
        const int p = R2 * 8 - R2 * (R2 - 1) / 2 + (d - R2);
        atomicAdd(dst + (size_t)(p * 2 + 0) * Ff, ar[s]);
        atomicAdd(dst + (size_t)(p * 2 + 1) * Ff, ai[s]);
    }
}

__global__ __launch_bounds__(64) void cov_accum(
    const float* __restrict__ target, const float* __restrict__ noise,
    float* __restrict__ covbuf)
{
    int f = blockIdx.x * 64 + threadIdx.x;
    if (f >= Ff) return;
    int n = blockIdx.y;
    int z = blockIdx.z;           // chunk*8 + inp*4 + g
    int g = z & 3;
    int inp = (z >> 2) & 1;
    int chunk = z >> 3;

    const float* src = inp ? noise : target;
    const float* base = src + (size_t)n * 2 * Cc * TFs + f;
    float* dst = covbuf + ((size_t)(inp * Nn + n) * 72) * Ff + f;
    int t0 = chunk * TCHUNK;

    switch (g) {
        case 0: cov_body<0>(base, dst, t0); break;
        case 1: cov_body<1>(base, dst, t0); break;
        case 2: cov_body<2>(base, dst, t0); break;
        default: cov_body<3>(base, dst, t0); break;
    }
}

// ---------------------------------------------------------------------------
// Stage 2: register-resident Gauss-Jordan solve of phiN * G = phiT.
// Block = 256 threads = 16 problems (f's). Load: 16 consecutive lanes read 16
// consecutive f's -> coalesced. 16 lanes per problem = 16 columns of the
// augmented [phiN | phiT]; shuffle broadcasts, no barriers in the GJ loop.
// ---------------------------------------------------------------------------
__global__ __launch_bounds__(256) void mvdr_weights(
    const float* __restrict__ covbuf, const int* __restrict__ ref_ptr,
    float2* __restrict__ wconj)
{
    const int tid = threadIdx.x;
    const int n = blockIdx.y;
    const int fbase = blockIdx.x * 16;

    __shared__ float cov[16][144];   // [prob][ target 72 | noise 72 ]

    {
        int f_off = tid & 15;
        int vrow = tid >> 4;          // 0..15
        int f = fbase + f_off;
#pragma unroll
        for (int b = 0; b < 9; ++b) {
            int v = b * 16 + vrow;    // 0..143; 0..71 target, 72..143 noise
            int inp = v >= 72 ? 1 : 0;
            int p2 = v - 72 * inp;
            float val = 0.f;
            if (f < Ff)
                val = covbuf[((size_t)(inp * Nn + n) * 72 + p2) * Ff + f];
            cov[f_off][v] = val;
        }
    }
    __syncthreads();

    const int prob = tid >> 4;        // 0..15
    const int col = tid & 15;
    const int f = fbase + prob;

    const float invT = 1.0f / (float)Tt;
    const float dl = 0.001f / 1.41421356237309515f;  // 0.001/sqrt(2)

    float Ar[8], Ai[8];
    {
        const bool left = (col < 8);            // left = phiN, right = phiT
        const int c = left ? col : col - 8;
        const float* cv = &cov[prob][left ? 72 : 0];
#pragma unroll
        for (int r = 0; r < 8; ++r) {
            int lo = r <= c ? r : c, hi = r <= c ? c : r;
            int p = lo * 8 - lo * (lo - 1) / 2 + (hi - lo);
            float vr = cv[2 * p] * invT;
            float vi = cv[2 * p + 1] * invT;
            if (r > c) vi = -vi;                // Hermitian reconstruction
            if (left && r == c) { vr += dl; vi += dl; }  // complex diag load
            Ar[r] = vr; Ai[r] = vi;
        }
    }

#pragma unroll
    for (int k = 0; k < 8; ++k) {
        // pivot search on column k (lane k's result is broadcast)
        int best = k;
        float bm = Ar[k] * Ar[k] + Ai[k] * Ai[k];
#pragma unroll
        for (int j = 0; j < 8; ++j) {
            if (j > k) {
                float m = Ar[j] * Ar[j] + Ai[j] * Ai[j];
                if (m > bm) { bm = m; best = j; }
            }
        }
        int bk = __shfl(best, k, 16);

        float tr = Ar[k], ti = Ai[k];
#pragma unroll
        for (int j = 0; j < 8; ++j) {
            if (j == bk && j != k) {
                Ar[k] = Ar[j]; Ai[k] = Ai[j];
                Ar[j] = tr;    Ai[j] = ti;
            }
        }

        float pr = __shfl(Ar[k], k, 16);
        float pi = __shfl(Ai[k], k, 16);
        float d = pr * pr + pi * pi;
        float ir = pr / d, ii = -pi / d;
        float nr = Ar[k] * ir - Ai[k] * ii;
        float ni = Ar[k] * ii + Ai[k] * ir;
        Ar[k] = nr; Ai[k] = ni;

#pragma unroll
        for (int r = 0; r < 8; ++r) {
            float fr = __shfl(Ar[r], k, 16);
            float fi = __shfl(Ai[r], k, 16);
            if (r != k) {
                Ar[r] -= fr * Ar[k] - fi * Ai[k];
                Ai[r] -= fr * Ai[k] + fi * Ar[k];
            }
        }
    }

    // trace(G): lane 8+j holds G[j][j]; butterfly over the 16-lane group
    float tlr = 0.f, tli = 0.f;
    if (col >= 8) { tlr = Ar[col - 8]; tli = Ai[col - 8]; }
#pragma unroll
    for (int off = 1; off < 16; off <<= 1) {
        tlr += __shfl_xor(tlr, off, 16);
        tli += __shfl_xor(tli, off, 16);
    }

    int ref = *ref_ptr;
    if (col == 8 + ref && f < Ff) {
        float den = tlr * tlr + tli * tli;
        float2* wp = wconj + ((size_t)n * Ff + f) * 8;
#pragma unroll
        for (int r = 0; r < 8; ++r) {
            float wx = (Ar[r] * tlr + Ai[r] * tli) / den;
            float wy = (Ai[r] * tlr - Ar[r] * tli) / den;
            wp[r] = make_float2(wx, -wy);   // conj(W)
        }
    }
}

// ---------------------------------------------------------------------------
// Stage 3: X_bf(n,t,f) = sum_c conj(W)(n,f,c) * y(n,c,t,f), float2 over flat
// (t,f). Adjacent flat positions are memory-adjacent in y and out.
// ---------------------------------------------------------------------------
__global__ __launch_bounds__(256) void beamform(
    const float* __restrict__ y, const float2* __restrict__ wconj,
    float* __restrict__ out)
{
    int idx = blockIdx.x * 256 + threadIdx.x;   // < N*TFs/2 = 262656
    int n = idx / (TFs / 2);
    int m = (idx - n * (TFs / 2)) * 2;          // even flat position t*Ff+f
    int f0 = m % Ff;
    int f1 = (f0 + 1 == Ff) ? 0 : f0 + 1;

    const float2* yb = (const float2*)y + ((size_t)n * 2 * Cc * TFs + m) / 2;
    const float2* w0 = wconj + ((size_t)n * Ff + f0) * 8;
    const float2* w1 = wconj + ((size_t)n * Ff + f1) * 8;

    float xr0 = 0.f, xi0 = 0.f, xr1 = 0.f, xi1 = 0.f;
#pragma unroll
    for (int c = 0; c < Cc; ++c) {
        float2 yre = yb[(size_t)c * (TFs / 2)];
        float2 yim = yb[(size_t)(Cc + c) * (TFs / 2)];
        float2 a = w0[c], b = w1[c];
        xr0 += a.x * yre.x - a.y * yim.x;
        xi0 += a.x * yim.x + a.y * yre.x;
        xr1 += b.x * yre.y - b.y * yim.y;
        xi1 += b.x * yim.y + b.y * yre.y;
    }
    size_t ob = ((size_t)n * 2 * TFs + m) / 2;   // float2 units
    ((float2*)out)[ob] = make_float2(xr0, xr1);           // real plane
    ((float2*)out)[ob + TFs / 2] = make_float2(xi0, xi1); // imag plane
}

extern "C" void kernel_launch(void* const* d_in, const int* in_sizes, int n_in,
                              void* d_out, int out_size, void* d_ws, size_t ws_size,
                              hipStream_t stream) {
    const float* mixture = (const float*)d_in[0];
    const float* target  = (const float*)d_in[1];
    const float* noise   = (const float*)d_in[2];
    const int*   refp    = (const int*)d_in[3];
    float* out = (float*)d_out;

    float*  covbuf = (float*)d_ws;
    float2* wconj  = (float2*)((char*)d_ws + COV_BYTES);

    // zero the atomic accumulator (ws is re-poisoned 0xAA before every launch)
    hipMemsetAsync(d_ws, 0, COV_BYTES, stream);

    cov_accum<<<dim3(9, Nn, NCHUNK * 8), 64, 0, stream>>>(target, noise, covbuf);
    mvdr_weights<<<dim3((Ff + 15) / 16, Nn), 256, 0, stream>>>(covbuf, refp, wconj);
    beamform<<<dim3((Nn * TFs / 2) / 256), 256, 0, stream>>>(mixture, wconj, out);
}

// Round 6
// 167.465 us; speedup vs baseline: 1.1987x; 1.0467x over previous
//
#include <hip/hip_runtime.h>

// mixture/target/noise: (N, 2, C, T, F) float32
#define Nn 4
#define Cc 8
#define Tt 256
#define Ff 513
#define TFs (Tt * Ff)      // 131328
#define NPAIR 36           // upper triangle of 8x8 Hermitian
#define NCHUNK 16
#define TCHUNK (Tt / NCHUNK)   // 16

// partial buffer: [inp(2)][n(4)][chunk(16)][p*2+ri (72)][f(513)] floats
#define PARTIAL_FLOATS ((size_t)2 * Nn * NCHUNK * 72 * Ff)
#define PARTIAL_BYTES  (PARTIAL_FLOATS * 4)   // ~18.9 MB

// ---------------------------------------------------------------------------
// Stage 1: partial covariances. Pair-group G handles Hermitian rows {G, 7-G}
// = 9 pairs -> 18 acc VGPRs (VGPR=32, no spill — R5-verified). 4608 one-wave
// blocks (~4.5 waves/SIMD) hide load latency (R5: occupancy was the fix).
// Plain coalesced stores — NO atomics (R5: 41 MB atomic write-through cost
// ~30 µs of serialization).
// ---------------------------------------------------------------------------
template <int G>
__device__ __forceinline__ void cov_body(const float* __restrict__ base,
                                         float* __restrict__ dst, int t0)
{
    constexpr int R2 = 7 - G;
    float ar[9], ai[9];
#pragma unroll
    for (int s = 0; s < 9; ++s) { ar[s] = 0.f; ai[s] = 0.f; }

    const float* bt = base + (size_t)t0 * Ff;
#pragma unroll
    for (int tt = 0; tt < TCHUNK; ++tt) {
        float re[8], im[8];
#pragma unroll
        for (int c = G; c < 8; ++c) {
            re[c] = bt[(size_t)c * TFs];
            im[c] = bt[(size_t)(Cc + c) * TFs];
        }
        int s = 0;
#pragma unroll
        for (int d = G; d < 8; ++d, ++s) {     // row G
            ar[s] += re[G] * re[d] + im[G] * im[d];
            ai[s] += im[G] * re[d] - re[G] * im[d];
        }
#pragma unroll
        for (int d = R2; d < 8; ++d, ++s) {    // row 7-G
            ar[s] += re[R2] * re[d] + im[R2] * im[d];
            ai[s] += im[R2] * re[d] - re[R2] * im[d];
        }
        bt += Ff;
    }

    int s = 0;
#pragma unroll
    for (int d = G; d < 8; ++d, ++s) {
        const int p = G * 8 - G * (G - 1) / 2 + (d - G);
        dst[(size_t)(p * 2 + 0) * Ff] = ar[s];
        dst[(size_t)(p * 2 + 1) * Ff] = ai[s];
    }
#pragma unroll
    for (int d = R2; d < 8; ++d, ++s) {
        const int p = R2 * 8 - R2 * (R2 - 1) / 2 + (d - R2);
        dst[(size_t)(p * 2 + 0) * Ff] = ar[s];
        dst[(size_t)(p * 2 + 1) * Ff] = ai[s];
    }
}

__global__ __launch_bounds__(64) void cov_partial(
    const float* __restrict__ target, const float* __restrict__ noise,
    float* __restrict__ partial)
{
    int f = blockIdx.x * 64 + threadIdx.x;
    if (f >= Ff) return;
    int n = blockIdx.y;
    int z = blockIdx.z;           // chunk*8 + inp*4 + g
    int g = z & 3;
    int inp = (z >> 2) & 1;
    int chunk = z >> 3;

    const float* src = inp ? noise : target;
    const float* base = src + (size_t)n * 2 * Cc * TFs + f;
    float* dst = partial +
        (((size_t)(inp * Nn + n) * NCHUNK + chunk) * 72) * Ff + f;
    int t0 = chunk * TCHUNK;

    switch (g) {
        case 0: cov_body<0>(base, dst, t0); break;
        case 1: cov_body<1>(base, dst, t0); break;
        case 2: cov_body<2>(base, dst, t0); break;
        default: cov_body<3>(base, dst, t0); break;
    }
}

// ---------------------------------------------------------------------------
// Stage 2: fused chunk-reduce + register-resident Gauss-Jordan.
// Block = 256 threads = 16 problems (f's). Reduce: 16 consecutive lanes read
// 16 consecutive f's -> 64B-coalesced; 9 v-rows/thread x 16 chunks, all
// independent loads. GJ: 16 lanes = 16 columns of augmented [phiN | phiT];
// shuffle broadcasts, no barriers.
// ---------------------------------------------------------------------------
__global__ __launch_bounds__(256) void mvdr_weights(
    const float* __restrict__ partial, const int* __restrict__ ref_ptr,
    float2* __restrict__ wconj)
{
    const int tid = threadIdx.x;
    const int n = blockIdx.y;
    const int fbase = blockIdx.x * 16;

    __shared__ float cov[16][144];   // [prob][ target 72 | noise 72 ]

    {
        int f_off = tid & 15;
        int vrow = tid >> 4;          // 0..15
        int f = fbase + f_off;
#pragma unroll
        for (int b = 0; b < 9; ++b) {
            int v = b * 16 + vrow;    // 0..143; 0..71 target, 72..143 noise
            int inp = v >= 72 ? 1 : 0;
            int p2 = v - 72 * inp;
            float acc = 0.f;
            if (f < Ff) {
                const float* src = partial +
                    ((size_t)(inp * Nn + n) * NCHUNK * 72 + p2) * Ff + f;
#pragma unroll
                for (int ch = 0; ch < NCHUNK; ++ch)
                    acc += src[(size_t)ch * 72 * Ff];
            }
            cov[f_off][v] = acc;
        }
    }
    __syncthreads();

    const int prob = tid >> 4;        // 0..15
    const int col = tid & 15;
    const int f = fbase + prob;

    const float invT = 1.0f / (float)Tt;
    const float dl = 0.001f / 1.41421356237309515f;  // 0.001/sqrt(2)

    float Ar[8], Ai[8];
    {
        const bool left = (col < 8);            // left = phiN, right = phiT
        const int c = left ? col : col - 8;
        const float* cv = &cov[prob][left ? 72 : 0];
#pragma unroll
        for (int r = 0; r < 8; ++r) {
            int lo = r <= c ? r : c, hi = r <= c ? c : r;
            int p = lo * 8 - lo * (lo - 1) / 2 + (hi - lo);
            float vr = cv[2 * p] * invT;
            float vi = cv[2 * p + 1] * invT;
            if (r > c) vi = -vi;                // Hermitian reconstruction
            if (left && r == c) { vr += dl; vi += dl; }  // complex diag load
            Ar[r] = vr; Ai[r] = vi;
        }
    }

#pragma unroll
    for (int k = 0; k < 8; ++k) {
        // pivot search on column k (lane k's result is broadcast)
        int best = k;
        float bm = Ar[k] * Ar[k] + Ai[k] * Ai[k];
#pragma unroll
        for (int j = 0; j < 8; ++j) {
            if (j > k) {
                float m = Ar[j] * Ar[j] + Ai[j] * Ai[j];
                if (m > bm) { bm = m; best = j; }
            }
        }
        int bk = __shfl(best, k, 16);

        float tr = Ar[k], ti = Ai[k];
#pragma unroll
        for (int j = 0; j < 8; ++j) {
            if (j == bk && j != k) {
                Ar[k] = Ar[j]; Ai[k] = Ai[j];
                Ar[j] = tr;    Ai[j] = ti;
            }
        }

        float pr = __shfl(Ar[k], k, 16);
        float pi = __shfl(Ai[k], k, 16);
        float d = pr * pr + pi * pi;
        float ir = pr / d, ii = -pi / d;
        float nr = Ar[k] * ir - Ai[k] * ii;
        float ni = Ar[k] * ii + Ai[k] * ir;
        Ar[k] = nr; Ai[k] = ni;

#pragma unroll
        for (int r = 0; r < 8; ++r) {
            float fr = __shfl(Ar[r], k, 16);
            float fi = __shfl(Ai[r], k, 16);
            if (r != k) {
                Ar[r] -= fr * Ar[k] - fi * Ai[k];
                Ai[r] -= fr * Ai[k] + fi * Ar[k];
            }
        }
    }

    // trace(G): lane 8+j holds G[j][j]; butterfly over the 16-lane group
    float tlr = 0.f, tli = 0.f;
    if (col >= 8) { tlr = Ar[col - 8]; tli = Ai[col - 8]; }
#pragma unroll
    for (int off = 1; off < 16; off <<= 1) {
        tlr += __shfl_xor(tlr, off, 16);
        tli += __shfl_xor(tli, off, 16);
    }

    int ref = *ref_ptr;
    if (col == 8 + ref && f < Ff) {
        float den = tlr * tlr + tli * tli;
        float2* wp = wconj + ((size_t)n * Ff + f) * 8;
#pragma unroll
        for (int r = 0; r < 8; ++r) {
            float wx = (Ar[r] * tlr + Ai[r] * tli) / den;
            float wy = (Ai[r] * tlr - Ar[r] * tli) / den;
            wp[r] = make_float2(wx, -wy);   // conj(W)
        }
    }
}

// ---------------------------------------------------------------------------
// Stage 3: X_bf(n,t,f) = sum_c conj(W)(n,f,c) * y(n,c,t,f), float2 over flat
// (t,f). Adjacent flat positions are memory-adjacent in y and out.
// ---------------------------------------------------------------------------
__global__ __launch_bounds__(256) void beamform(
    const float* __restrict__ y, const float2* __restrict__ wconj,
    float* __restrict__ out)
{
    int idx = blockIdx.x * 256 + threadIdx.x;   // < N*TFs/2 = 262656
    int n = idx / (TFs / 2);
    int m = (idx - n * (TFs / 2)) * 2;          // even flat position t*Ff+f
    int f0 = m % Ff;
    int f1 = (f0 + 1 == Ff) ? 0 : f0 + 1;

    const float2* yb = (const float2*)y + ((size_t)n * 2 * Cc * TFs + m) / 2;
    const float2* w0 = wconj + ((size_t)n * Ff + f0) * 8;
    const float2* w1 = wconj + ((size_t)n * Ff + f1) * 8;

    float xr0 = 0.f, xi0 = 0.f, xr1 = 0.f, xi1 = 0.f;
#pragma unroll
    for (int c = 0; c < Cc; ++c) {
        float2 yre = yb[(size_t)c * (TFs / 2)];
        float2 yim = yb[(size_t)(Cc + c) * (TFs / 2)];
        float2 a = w0[c], b = w1[c];
        xr0 += a.x * yre.x - a.y * yim.x;
        xi0 += a.x * yim.x + a.y * yre.x;
        xr1 += b.x * yre.y - b.y * yim.y;
        xi1 += b.x * yim.y + b.y * yre.y;
    }
    size_t ob = ((size_t)n * 2 * TFs + m) / 2;   // float2 units
    ((float2*)out)[ob] = make_float2(xr0, xr1);           // real plane
    ((float2*)out)[ob + TFs / 2] = make_float2(xi0, xi1); // imag plane
}

extern "C" void kernel_launch(void* const* d_in, const int* in_sizes, int n_in,
                              void* d_out, int out_size, void* d_ws, size_t ws_size,
                              hipStream_t stream) {
    const float* mixture = (const float*)d_in[0];
    const float* target  = (const float*)d_in[1];
    const float* noise   = (const float*)d_in[2];
    const int*   refp    = (const int*)d_in[3];
    float* out = (float*)d_out;

    float*  partial = (float*)d_ws;
    float2* wconj   = (float2*)((char*)d_ws + PARTIAL_BYTES);

    cov_partial<<<dim3(9, Nn, NCHUNK * 8), 64, 0, stream>>>(
        target, noise, partial);
    mvdr_weights<<<dim3((Ff + 15) / 16, Nn), 256, 0, stream>>>(
        partial, refp, wconj);
    beamform<<<dim3((Nn * TFs / 2) / 256), 256, 0, stream>>>(mixture, wconj, out);
}